// Round 8
// baseline (635.253 us; speedup 1.0000x reference)
//
#include <hip/hip_runtime.h>

#define BB 32
#define NSTEP 31
#define CROW 1040
#define CB_STRIDE 266240L   // 1040*256 elems per b (Cb bf16 / Qf f32)
#define XB_STRIDE 16384L    // 64*256 elems per b (xb)
#define PPART 524288L       // 32*64*256 per projection part
#define RS 528              // LDS row stride bytes (132 dwords, %32=4 -> 2-way max)
#define BUF (64 * RS)

__device__ __constant__ int d_lens[NSTEP] = {63,62,61,60,59,58,57,56,55,54,53,52,51,50,49,
                                             24,23,22,21,20,19,18,17,
                                             8,7,6,5,4,3,2,1};
__device__ __constant__ int d_cb[NSTEP] = {0,63,125,186,246,305,363,420,476,531,585,638,690,741,791,
                                           840,864,887,909,930,950,969,987,
                                           1004,1012,1019,1025,1030,1034,1037,1039};

typedef short v8s __attribute__((ext_vector_type(8)));
typedef float v4f __attribute__((ext_vector_type(4)));

__device__ __forceinline__ unsigned short rne_bf16(float f) {
    unsigned int u = __float_as_uint(f);
    u = (u + 0x7FFFu + ((u >> 16) & 1u)) >> 16;
    return (unsigned short)u;
}

#define MFMA16 __builtin_amdgcn_mfma_f32_16x16x32_bf16

// waitcnt+barrier in ONE asm so no memory op can slip between them.
// Skips vmcnt drain: global stores (Cb) are per-wave-disjoint, read only by
// later dispatches; LDS ordering handled by lgkmcnt(0).
__device__ __forceinline__ void lds_barrier() {
    asm volatile("s_waitcnt lgkmcnt(0)\n\ts_barrier" ::: "memory");
}

// One-shot dtype/layout prep:
//  xb [32][64][256]    bf16 <- x[32][256][64]      (time-major transpose)
//  w2t[29*256][2][256] bf16 <- w2[29*256][256][2]  (k-major transpose)
//  w3t[2*256][3][256]  bf16 <- w3[2*256][256][3]
//  vwb[256][768]       bf16 <- vw
__global__ __launch_bounds__(256)
void prep(const float* __restrict__ x, const float* __restrict__ w2,
          const float* __restrict__ w3, const float* __restrict__ vw,
          unsigned short* __restrict__ xb, unsigned short* __restrict__ w2t,
          unsigned short* __restrict__ w3t, unsigned short* __restrict__ vwb)
{
    long idx = (long)blockIdx.x * 256 + threadIdx.x;
    if (idx < 524288) {                       // xb
        const int ci = idx & 255, l = (idx >> 8) & 63, b = (int)(idx >> 14);
        xb[idx] = rne_bf16(x[((long)b << 14) + ((long)ci << 6) + l]);
        return;
    }
    idx -= 524288;
    if (idx < 3801088) {                      // w2t
        const int ci = idx & 255, k = (idx >> 8) & 1; const long row = idx >> 9;
        w2t[idx] = rne_bf16(w2[row * 512 + ci * 2 + k]);
        return;
    }
    idx -= 3801088;
    if (idx < 393216) {                       // w3t
        const int ci = idx & 255; const long r = idx >> 8;
        const int k = (int)(r % 3); const long row = r / 3;
        w3t[idx] = rne_bf16(w3[row * 768 + ci * 3 + k]);
        return;
    }
    idx -= 393216;
    if (idx < 196608) vwb[idx] = rne_bf16(vw[idx]);
}

// ---- conv steps (activations LDS-resident, weights from L2) --------------
// LDS tile [64 rows][256 ch] bf16, row stride RS bytes.
// B-frag (l, ki): (l*S + ki>>3)*RS + (ki&7)*64 + g*16.

// Big path (nt==4, L>=49): wave = 2 m-tiles x 2 l-tiles.
template<int KC, int S>
__device__ __forceinline__ void conv_big(
    const unsigned short* __restrict__ Wt, const float* __restrict__ bias,
    const char* in, char* out, unsigned short* __restrict__ Cbp,
    int L, int wave, int nl, int g)
{
    const int wm = wave >> 1;        // m-tiles 2wm, 2wm+1
    const int lg2 = wave & 1;        // l-tiles 2lg2, 2lg2+1
    const int l0 = lg2 * 32 + nl, l1 = l0 + 16;
    const int lv0 = min(l0, L - 1), lv1 = min(l1, L - 1);

    v4f a00 = {0,0,0,0}, a01 = {0,0,0,0}, a10 = {0,0,0,0}, a11 = {0,0,0,0};
    const unsigned short* A0 = Wt + (size_t)(wm * 32 + nl) * (KC * 256) + g * 8;
    const unsigned short* A1 = A0 + (size_t)16 * (KC * 256);

    #pragma unroll
    for (int c = 0; c < KC; ++c) {
        v8s wf0[8], wf1[8];
        #pragma unroll
        for (int k = 0; k < 8; ++k) {
            wf0[k] = *(const v8s*)(A0 + (c * 8 + k) * 32);
            wf1[k] = *(const v8s*)(A1 + (c * 8 + k) * 32);
        }
        const char* rp0 = in + (lv0 * S + c) * RS + g * 16;
        const char* rp1 = in + (lv1 * S + c) * RS + g * 16;
        #pragma unroll
        for (int k = 0; k < 8; ++k) {
            const v8s b0 = *(const v8s*)(rp0 + k * 64);
            const v8s b1 = *(const v8s*)(rp1 + k * 64);
            a00 = MFMA16(wf0[k], b0, a00, 0, 0, 0);
            a10 = MFMA16(wf1[k], b0, a10, 0, 0, 0);
            a01 = MFMA16(wf0[k], b1, a01, 0, 0, 0);
            a11 = MFMA16(wf1[k], b1, a11, 0, 0, 0);
        }
    }
    const int m0 = wm * 32 + g * 4;
    const float4 bv0 = *(const float4*)(bias + m0);
    const float4 bv1 = *(const float4*)(bias + m0 + 16);
    #pragma unroll
    for (int li = 0; li < 2; ++li) {
        const int l = li ? l1 : l0;
        if (l < L) {
            const v4f aa = li ? a01 : a00;
            const v4f ab = li ? a11 : a10;
            ushort4 p0, p1;
            p0.x = rne_bf16(aa[0] + bv0.x); p0.y = rne_bf16(aa[1] + bv0.y);
            p0.z = rne_bf16(aa[2] + bv0.z); p0.w = rne_bf16(aa[3] + bv0.w);
            p1.x = rne_bf16(ab[0] + bv1.x); p1.y = rne_bf16(ab[1] + bv1.y);
            p1.z = rne_bf16(ab[2] + bv1.z); p1.w = rne_bf16(ab[3] + bv1.w);
            *(ushort4*)(out + l * RS + m0 * 2) = p0;
            *(ushort4*)(out + l * RS + (m0 + 16) * 2) = p1;
            *(ushort4*)(Cbp + (size_t)l * 256 + m0) = p0;
            *(ushort4*)(Cbp + (size_t)l * 256 + m0 + 16) = p1;
        }
    }
}

// Small path (nt<=2, L<=24): wave = 1 m-tile x nt l-tiles.
template<int KC, int S, bool TWO_L>
__device__ __forceinline__ void conv_small(
    const unsigned short* __restrict__ Wt, const float* __restrict__ bias,
    const char* in, char* out, unsigned short* __restrict__ Cbp,
    int L, int wave, int nl, int g)
{
    const int lv0 = min(nl, L - 1);
    const int lv1 = min(16 + nl, L - 1);

    v4f a0 = {0,0,0,0}, a1 = {0,0,0,0};
    const unsigned short* A0 = Wt + (size_t)(wave * 16 + nl) * (KC * 256) + g * 8;

    #pragma unroll
    for (int c = 0; c < KC; ++c) {
        v8s wf[8];
        #pragma unroll
        for (int k = 0; k < 8; ++k)
            wf[k] = *(const v8s*)(A0 + (c * 8 + k) * 32);
        const char* rp0 = in + (lv0 * S + c) * RS + g * 16;
        const char* rp1 = in + (lv1 * S + c) * RS + g * 16;
        #pragma unroll
        for (int k = 0; k < 8; ++k) {
            const v8s b0 = *(const v8s*)(rp0 + k * 64);
            a0 = MFMA16(wf[k], b0, a0, 0, 0, 0);
            if (TWO_L) {
                const v8s b1 = *(const v8s*)(rp1 + k * 64);
                a1 = MFMA16(wf[k], b1, a1, 0, 0, 0);
            }
        }
    }
    const int m0 = wave * 16 + g * 4;
    const float4 bv = *(const float4*)(bias + m0);
    {
        const int l = nl;
        if (l < L) {
            ushort4 pk;
            pk.x = rne_bf16(a0[0] + bv.x); pk.y = rne_bf16(a0[1] + bv.y);
            pk.z = rne_bf16(a0[2] + bv.z); pk.w = rne_bf16(a0[3] + bv.w);
            *(ushort4*)(out + l * RS + m0 * 2) = pk;
            *(ushort4*)(Cbp + (size_t)l * 256 + m0) = pk;
        }
    }
    if (TWO_L) {
        const int l = 16 + nl;
        if (l < L) {
            ushort4 pk;
            pk.x = rne_bf16(a1[0] + bv.x); pk.y = rne_bf16(a1[1] + bv.y);
            pk.z = rne_bf16(a1[2] + bv.z); pk.w = rne_bf16(a1[3] + bv.w);
            *(ushort4*)(out + l * RS + m0 * 2) = pk;
            *(ushort4*)(Cbp + (size_t)l * 256 + m0) = pk;
        }
    }
}

__global__ __launch_bounds__(1024, 4)
void chain(const unsigned short* __restrict__ xb,
           const unsigned short* __restrict__ w2t,
           const unsigned short* __restrict__ w3t,
           const float* __restrict__ b2, const float* __restrict__ b3,
           unsigned short* __restrict__ Cb)
{
    __shared__ __align__(16) char lds[2 * BUF];
    const int b = blockIdx.x;
    const int tid = threadIdx.x;
    const int wave = tid >> 6, lane = tid & 63, nl = lane & 15, g = lane >> 4;

    char* base = lds;

    // stage x into buf0
    {
        const unsigned short* src = xb + (size_t)b * XB_STRIDE;
        #pragma unroll
        for (int i = 0; i < 2; ++i) {
            const int c = tid + i * 1024;
            const int r = c >> 5, cc = c & 31;
            const v8s v = *(const v8s*)(src + r * 256 + cc * 8);
            *(v8s*)(base + r * RS + cc * 16) = v;
        }
    }
    lds_barrier();

    unsigned short* Cbb = Cb + (size_t)b * CB_STRIDE;
    int cur = 0, i2 = 0, i3 = 0;
    for (int t = 0; t < NSTEP; ++t) {
        const int L = d_lens[t];
        char* inb  = base + cur * BUF;
        char* outb = base + (cur ^ 1) * BUF;
        unsigned short* Cbp = Cbb + (size_t)d_cb[t] * 256;
        if (t < 15) {
            conv_big<2, 1>(w2t + (size_t)i2 * 131072, b2 + i2 * 256,
                           inb, outb, Cbp, L, wave, nl, g);
            ++i2;
        } else if (t == 15) {
            conv_small<3, 2, true>(w3t, b3, inb, outb, Cbp, L, wave, nl, g);
            ++i3;
        } else if (t < 23) {
            conv_small<2, 1, true>(w2t + (size_t)i2 * 131072, b2 + i2 * 256,
                                   inb, outb, Cbp, L, wave, nl, g);
            ++i2;
        } else if (t == 23) {
            conv_small<3, 2, false>(w3t + 196608, b3 + 256,
                                    inb, outb, Cbp, L, wave, nl, g);
            ++i3;
        } else {
            conv_small<2, 1, false>(w2t + (size_t)i2 * 131072, b2 + i2 * 256,
                                    inb, outb, Cbp, L, wave, nl, g);
            ++i2;
        }
        lds_barrier();
        cur ^= 1;
    }
}

// MFMA GEMM for Q and P (round-4 verified).
// OMODE 1: f32 out Qf[b][l][m]; OMODE 2: f32 out P[p][b][m][l]
template<int OMODE>
__global__ __launch_bounds__(256)
void mg(const unsigned short* __restrict__ A, int arow, int acol0,
        const unsigned short* __restrict__ B, long bbstr,
        void* __restrict__ OUT)
{
    const int lane = threadIdx.x & 63;
    const int wave = threadIdx.x >> 6;
    const int nl = lane & 15, g = lane >> 4;
    const int n = blockIdx.x * 16 + nl;
    const int b = n & 31;
    const int l = n >> 5;
    const int p = blockIdx.y;

    const unsigned short* Ab = A + (size_t)(wave * 64 + nl) * arow + acol0 + p * 256 + g * 8;
    const unsigned short* Bb = B + (size_t)b * bbstr + (size_t)l * 256 + g * 8;

    v4f acc[4] = {};
    #pragma unroll
    for (int k = 0; k < 8; ++k) {
        const v8s bf = *(const v8s*)(Bb + k * 32);
        #pragma unroll
        for (int mf = 0; mf < 4; ++mf) {
            const v8s af = *(const v8s*)(Ab + (size_t)mf * 16 * arow + k * 32);
            acc[mf] = MFMA16(af, bf, acc[mf], 0, 0, 0);
        }
    }
    #pragma unroll
    for (int mf = 0; mf < 4; ++mf) {
        const int m0 = wave * 64 + mf * 16 + g * 4;
        if constexpr (OMODE == 1) {
            *(v4f*)((float*)OUT + (size_t)b * CB_STRIDE + (size_t)l * 256 + m0) = acc[mf];
        } else {
            float* Po = (float*)OUT + (size_t)p * PPART + (size_t)b * XB_STRIDE + l;
            #pragma unroll
            for (int r = 0; r < 4; ++r) Po[(size_t)(m0 + r) * 64] = acc[mf][r];
        }
    }
}

// out[b,o,i,j] = vis_b[o]                          (unset)
//             + Pl[b,o,i]+Pm[b,o,i]+Pr[b,o,i]      (diag)
//             + Pl[b,o,i]+Q[b,q,o]+Pr[b,o,j]       (set off-diag)
__global__ __launch_bounds__(256)
void final_k(const float* __restrict__ P, const float* __restrict__ Qb,
             const float* __restrict__ vb, float* __restrict__ out)
{
    const int b = blockIdx.x >> 6;
    const int i = blockIdx.x & 63;
    const int t = threadIdx.x;
    const int j = t & 63;
    const int os = t >> 6;

    __shared__ int qidx[64];
    if (t < 64) {
        const int d = t - i;
        int v = -1;
        if (t == i) v = -2;
        else if (d >= 1 && d <= 15) v = d_cb[d-1] + i;
        else if (d >= 17 && d <= 31 && (d & 1) && !(i & 1)) v = d_cb[15 + ((d-17)>>1)] + (i>>1);
        else if (d >= 35 && d <= 63 && ((d-35)&3)==0 && !(i&3)) v = d_cb[23 + ((d-35)>>2)] + (i>>2);
        qidx[t] = v;
    }
    __syncthreads();
    const int q = qidx[j];

    for (int oc = 0; oc < 64; ++oc) {
        const int o = oc * 4 + os;
        const float pl = P[(size_t)(b * 256 + o) * 64 + i];
        const float pm = P[524288u + (size_t)(b * 256 + o) * 64 + i];
        const float* pr = P + 1048576u + (size_t)(b * 256 + o) * 64;
        const float vbv = vb[o];
        float v;
        if (q == -2)      v = pl + pm + pr[i] + vbv;
        else if (q >= 0)  v = pl + Qb[(size_t)b * CB_STRIDE + (size_t)q * 256 + o] + pr[j] + vbv;
        else              v = vbv;
        out[(((size_t)b * 256 + o) * 64 + i) * 64 + j] = v;
    }
}

extern "C" void kernel_launch(void* const* d_in, const int* in_sizes, int n_in,
                              void* d_out, int out_size, void* d_ws, size_t ws_size,
                              hipStream_t stream)
{
    const float* x   = (const float*)d_in[0];
    const float* w2  = (const float*)d_in[1];
    const float* b2  = (const float*)d_in[2];
    const float* w3  = (const float*)d_in[3];
    const float* b3  = (const float*)d_in[4];
    const float* vw  = (const float*)d_in[5];
    const float* vb  = (const float*)d_in[6];
    float* out = (float*)d_out;

    // ws: Qf 34.08M | P 6.29M | Cb 17.04M | xb 1.05M | w2t 7.60M | w3t 0.79M | vwb 0.39M
    char* w = (char*)d_ws;
    float*          Qf  = (float*)w;          w += (size_t)BB * CB_STRIDE * 4;
    float*          P   = (float*)w;          w += (size_t)3 * PPART * 4;
    unsigned short* Cb  = (unsigned short*)w; w += (size_t)BB * CB_STRIDE * 2;
    unsigned short* xb  = (unsigned short*)w; w += (size_t)BB * XB_STRIDE * 2;
    unsigned short* w2t = (unsigned short*)w; w += (size_t)29 * 131072 * 2;
    unsigned short* w3t = (unsigned short*)w; w += (size_t)2 * 196608 * 2;
    unsigned short* vwb = (unsigned short*)w;

    prep<<<dim3(19200), 256, 0, stream>>>(x, w2, w3, vw, xb, w2t, w3t, vwb);
    // P projections (only need xb): overlaps nothing but independent of chain
    mg<2><<<dim3(128, 3), 256, 0, stream>>>(vwb, 768, 0, xb, XB_STRIDE, P);
    chain<<<dim3(BB), 1024, 0, stream>>>(xb, w2t, w3t, b2, b3, Cb);
    mg<1><<<dim3(2080, 1), 256, 0, stream>>>(vwb, 768, 256, Cb, CB_STRIDE, Qf);
    final_k<<<dim3(BB * 64), 256, 0, stream>>>(P, Qf, vb, out);
}